// Round 13
// baseline (820.291 us; speedup 1.0000x reference)
//
#include <hip/hip_runtime.h>
#include <hip/hip_bf16.h>
#include <cstdint>
#include <cmath>

typedef __bf16 bf16;
typedef __bf16 bf16x8 __attribute__((ext_vector_type(8)));
typedef __bf16 bf16x4 __attribute__((ext_vector_type(4)));
typedef __bf16 bf16x2 __attribute__((ext_vector_type(2)));
typedef float f32x4 __attribute__((ext_vector_type(4)));

#define NROWS 8192
#define UNITS 2048
#define NT 64      // K = 4096 / BK(=64)
#define NSPLIT 32  // tile index where A switches from A0 to A1

__device__ __forceinline__ void gload_lds16(const bf16* g, const bf16* lds) {
  __builtin_amdgcn_global_load_lds(
      (const __attribute__((address_space(1))) uint32_t*)(uintptr_t)g,
      (__attribute__((address_space(3))) uint32_t*)(uint32_t)(uintptr_t)lds,
      16, 0, 0);
}

#define BARR do { asm volatile("" ::: "memory"); __builtin_amdgcn_s_barrier(); \
                  asm volatile("" ::: "memory"); } while (0)
#define WAITV(N) asm volatile("s_waitcnt vmcnt(" #N ")" ::: "memory")

__device__ __forceinline__ float fast_tanh(float v) {
  float e = __expf(2.f * v);  // saturates: +inf -> 1, 0 -> -1; no NaN
  return 1.f - 2.f / (e + 1.f);
}

// ---- pack x,y fp32 -> bf16
__global__ void pack_xy_kernel(const float* __restrict__ x, const float* __restrict__ y,
                               bf16* __restrict__ xb, bf16* __restrict__ yb) {
  size_t n4 = (size_t)NROWS * UNITS / 4;
  size_t stride = (size_t)gridDim.x * blockDim.x;
  for (size_t i = (size_t)blockIdx.x * blockDim.x + threadIdx.x; i < n4; i += stride) {
    float4 vx = ((const float4*)x)[i];
    float4 vy = ((const float4*)y)[i];
    bf16x4 ox = {(bf16)vx.x, (bf16)vx.y, (bf16)vx.z, (bf16)vx.w};
    bf16x4 oy = {(bf16)vy.x, (bf16)vy.y, (bf16)vy.z, (bf16)vy.w};
    ((bf16x4*)xb)[i] = ox;
    ((bf16x4*)yb)[i] = oy;
  }
}

// ---- fused 6-way transpose+convert, 64(k) x 32(j) tiles, bf16x2 stores (128B rows)
__global__ void transpose_cvt6_kernel(const float* __restrict__ Wz, const float* __restrict__ Uz,
                                      const float* __restrict__ Wr, const float* __restrict__ Ur,
                                      const float* __restrict__ Wg, const float* __restrict__ Ug,
                                      bf16* __restrict__ Bzr, bf16* __restrict__ Bgt) {
  __shared__ float t[64][33];
  const float* src;
  bf16* dst;
  int koff;
  switch (blockIdx.z) {
    case 0: src = Wz; dst = Bzr;                         koff = 0;    break;
    case 1: src = Uz; dst = Bzr;                         koff = 2048; break;
    case 2: src = Wr; dst = Bzr + (size_t)2048 * 4096;   koff = 0;    break;
    case 3: src = Ur; dst = Bzr + (size_t)2048 * 4096;   koff = 2048; break;
    case 4: src = Wg; dst = Bgt;                         koff = 0;    break;
    default: src = Ug; dst = Bgt;                        koff = 2048; break;
  }
  int j0 = blockIdx.x * 32, k0 = blockIdx.y * 64;
  int tx = threadIdx.x & 31, ty = threadIdx.x >> 5;  // 32 x 8
#pragma unroll
  for (int i = 0; i < 64; i += 8)
    t[ty + i][tx] = src[(size_t)(k0 + ty + i) * UNITS + j0 + tx];
  __syncthreads();
#pragma unroll
  for (int i = 0; i < 32; i += 8) {
    int j = j0 + ty + i;
    bf16x2 v = {(bf16)t[2 * tx][ty + i], (bf16)t[2 * tx + 1][ty + i]};
    *(bf16x2*)&dst[(size_t)j * 4096 + koff + k0 + 2 * tx] = v;
  }
}

// ===== 256x256 single-barrier double-buffer GEMM (1 barrier + 1 vmcnt per K-tile) =====
template <int EPI>
__global__ __launch_bounds__(512, 2)
void gemm256(const bf16* __restrict__ A0, const bf16* __restrict__ A1,
             const bf16* __restrict__ Bt,
             const float* __restrict__ bias_a, const float* __restrict__ bias_b,
             const float* __restrict__ bias_c, const float* __restrict__ bias_d,
             const bf16* __restrict__ xin, bf16* __restrict__ zbuf,
             bf16* __restrict__ rxbuf, float* __restrict__ outbuf) {
  __shared__ bf16 LDS[2][32768];  // per buf: A[0,16384) B[16384,32768)
  const int tid = threadIdx.x;
  const int wv = tid >> 6, lane = tid & 63;
  const int wr = wv >> 2, wc = wv & 3;

  // 2-D XCD patch mapping (L2 reuse for both A and B panels)
  const int nl = (int)gridDim.x >> 3;
  const int xc = (int)blockIdx.x & 7;
  const int l = (int)blockIdx.x >> 3;
  const int bxq = nl >> 4;
  const int by = (xc & 1) * 16 + (l & 15);
  const int bx = (xc >> 1) * bxq + (l >> 4);
  const int brow = by * 256;
  const int bcol = bx * 256;

  // ---- staging offsets (inverse-swizzled source, linear LDS dest)
  const int rr = lane >> 2;
  const int kk_st = ((lane & 3) * 8) ^ ((rr & 6) << 2);
  int offA[2][2], offB[2][2], dstA[2][2], dstB[2][2];
#pragma unroll
  for (int H = 0; H < 2; ++H)
#pragma unroll
    for (int c = 0; c < 2; ++c) {
      int ssA = H * 8 + wv;
      offA[H][c] = (brow + c * 128 + (ssA >> 1) * 16 + rr) * 2048 + (ssA & 1) * 32 + kk_st;
      dstA[H][c] = c * 8192 + ssA * 512;
      int ssB = (wv >> 2) * 8 + H * 4 + (wv & 3);
      offB[H][c] = (bcol + c * 128 + (ssB >> 1) * 16 + rr) * 4096 + (ssB & 1) * 32 + kk_st;
      dstB[H][c] = 16384 + c * 8192 + ssB * 512;
    }

  // ---- fragment read offsets (swizzled; conflict-free 16x16 geometry)
  const int lr = lane & 15;
  const int kread = ((lane >> 4) * 8) ^ ((lr & 6) << 2);
  const int abase = wr * 8192 + lr * 32 + kread;
  const int bbase = 16384 + (wc >> 1) * 8192 + (wc & 1) * 4096 + lr * 32 + kread;

#define ST_A(TI, H, BUF)                                                      \
  if ((TI) < NT) {                                                            \
    const bf16* _s = ((TI) < NSPLIT) ? A0 + (size_t)(TI)*64                   \
                                     : A1 + (size_t)((TI)-NSPLIT) * 64;       \
    gload_lds16(_s + offA[H][0], (BUF) + dstA[H][0]);                         \
    gload_lds16(_s + offA[H][1], (BUF) + dstA[H][1]);                         \
  }
#define ST_B(TI, H, BUF)                                                      \
  if ((TI) < NT) {                                                            \
    const bf16* _s = Bt + (size_t)(TI)*64;                                    \
    gload_lds16(_s + offB[H][0], (BUF) + dstB[H][0]);                         \
    gload_lds16(_s + offB[H][1], (BUF) + dstB[H][1]);                         \
  }
#define RD_B(DST, LP, NB)                                                     \
  _Pragma("unroll") for (int kh = 0; kh < 2; ++kh)                            \
  _Pragma("unroll") for (int n = 0; n < 2; ++n)                               \
      DST[n][kh] = *(const bf16x8*)((LP) + bbase + ((n + 2 * (NB)) * 2 + kh) * 512);
#define RD_A(DST, LP, MB)                                                     \
  _Pragma("unroll") for (int kh = 0; kh < 2; ++kh)                            \
  _Pragma("unroll") for (int m = 0; m < 4; ++m)                               \
      DST[m][kh] = *(const bf16x8*)((LP) + abase + ((m + 4 * (MB)) * 2 + kh) * 512);
#define MFMA_Q(AARR, BARR_, MOFF, NOFF)                                       \
  __builtin_amdgcn_s_setprio(1);                                              \
  _Pragma("unroll") for (int kh = 0; kh < 2; ++kh)                            \
  _Pragma("unroll") for (int m = 0; m < 4; ++m)                               \
  _Pragma("unroll") for (int n = 0; n < 2; ++n)                               \
      acc[m + MOFF][n + NOFF] = __builtin_amdgcn_mfma_f32_16x16x32_bf16(      \
          AARR[m][kh], BARR_[n][kh], acc[m + MOFF][n + NOFF], 0, 0, 0);       \
  __builtin_amdgcn_s_setprio(0);

  f32x4 acc[8][4];
#pragma unroll
  for (int m = 0; m < 8; ++m)
#pragma unroll
    for (int n = 0; n < 4; ++n) {
      f32x4 zz = {0.f, 0.f, 0.f, 0.f};
      acc[m][n] = zz;
    }

  bf16x8 a0[4][2], a1[4][2], b0[2][2], b1[2][2];

  // ---- prologue: stage tile0 -> buf0; drain; barrier ----
  {
    bf16* L0 = &LDS[0][0];
    ST_A(0, 0, L0); ST_B(0, 0, L0); ST_A(0, 1, L0); ST_B(0, 1, L0);
    WAITV(0);
    BARR;
  }

  // Tile t: stage t+1 -> NXT; read all of t <- CUR (a0,b0,b1,a1 = consumption
  // order, compiler pipelines via per-consumer lgkmcnt); 64 MFMA; drain; barrier.
#define TILE(T, CUR, NXT)                                                     \
  {                                                                           \
    const bf16* Lc = &LDS[CUR][0];                                            \
    bf16* Lnw = &LDS[NXT][0];                                                 \
    ST_A((T) + 1, 0, Lnw);                                                    \
    ST_B((T) + 1, 0, Lnw);                                                    \
    ST_A((T) + 1, 1, Lnw);                                                    \
    ST_B((T) + 1, 1, Lnw);                                                    \
    RD_A(a0, Lc, 0);                                                          \
    RD_B(b0, Lc, 0);                                                          \
    RD_B(b1, Lc, 1);                                                          \
    RD_A(a1, Lc, 1);                                                          \
    MFMA_Q(a0, b0, 0, 0);                                                     \
    MFMA_Q(a0, b1, 0, 2);                                                     \
    MFMA_Q(a1, b0, 4, 0);                                                     \
    MFMA_Q(a1, b1, 4, 2);                                                     \
    WAITV(0); BARR;                                                           \
  }

#pragma unroll 1
  for (int t = 0; t < NT; t += 2) {
    TILE(t, 0, 1);
    TILE(t + 1, 1, 0);
  }

  // ---- epilogue: C/D layout col=lane&15, row=(lane>>4)*4+q ----
  const int lq = (lane >> 4) << 2;
  const int lc = lane & 15;
  const int rowb = brow + wr * 128;
  const int colb = bcol + wc * 64;
  if constexpr (EPI == 0) {
    if (bcol < UNITS) {
#pragma unroll
      for (int m = 0; m < 8; ++m)
#pragma unroll
        for (int n = 0; n < 4; ++n) {
          int col = colb + n * 16 + lc;
          float ba = bias_a[col] + bias_b[col];
#pragma unroll
          for (int q = 0; q < 4; ++q) {
            int row = rowb + m * 16 + lq + q;
            zbuf[(size_t)row * UNITS + col] = (bf16)(acc[m][n][q] + ba);
          }
        }
    } else {
#pragma unroll
      for (int m = 0; m < 8; ++m)
#pragma unroll
        for (int n = 0; n < 4; ++n) {
          int col = colb - UNITS + n * 16 + lc;
          float bc = bias_c[col] + bias_d[col];
#pragma unroll
          for (int q = 0; q < 4; ++q) {
            int row = rowb + m * 16 + lq + q;
            size_t idx = (size_t)row * UNITS + col;
            float r = acc[m][n][q] + bc;
            rxbuf[idx] = (bf16)(r * (float)xin[idx]);
          }
        }
    }
  } else {
#pragma unroll
    for (int m = 0; m < 8; ++m)
#pragma unroll
      for (int n = 0; n < 4; ++n) {
        int col = colb + n * 16 + lc;
        float bg_ = bias_a[col] + bias_b[col];
#pragma unroll
        for (int q = 0; q < 4; ++q) {
          int row = rowb + m * 16 + lq + q;
          size_t idx = (size_t)row * UNITS + col;
          float h = fast_tanh(acc[m][n][q] + bg_);
          float zv = (float)zbuf[idx];
          float xv = (float)xin[idx];
          outbuf[idx] = (1.f - zv) * xv + zv * h;
        }
      }
  }
#undef ST_A
#undef ST_B
#undef RD_A
#undef RD_B
#undef MFMA_Q
#undef TILE
}

extern "C" void kernel_launch(void* const* d_in, const int* in_sizes, int n_in,
                              void* d_out, int out_size, void* d_ws, size_t ws_size,
                              hipStream_t stream) {
  const float* x   = (const float*)d_in[0];
  const float* y   = (const float*)d_in[1];
  const float* Wz  = (const float*)d_in[2];
  const float* bz  = (const float*)d_in[3];
  const float* Uz  = (const float*)d_in[4];
  const float* buz = (const float*)d_in[5];
  const float* Wr  = (const float*)d_in[6];
  const float* br  = (const float*)d_in[7];
  const float* Ur  = (const float*)d_in[8];
  const float* bur = (const float*)d_in[9];
  const float* Wg  = (const float*)d_in[10];
  const float* bg  = (const float*)d_in[11];
  const float* Ug  = (const float*)d_in[12];
  const float* bug = (const float*)d_in[13];
  float* out = (float*)d_out;

  char* w = (char*)d_ws;
  bf16* Ybf = (bf16*)w;  w += (size_t)NROWS * UNITS * 2;  // 32 MiB
  bf16* Xbf = (bf16*)w;  w += (size_t)NROWS * UNITS * 2;  // 32 MiB
  bf16* RX  = (bf16*)w;  w += (size_t)NROWS * UNITS * 2;  // 32 MiB
  bf16* Bzr = (bf16*)w;  w += (size_t)4096 * 4096 * 2;    // 32 MiB
  bf16* Bgt = (bf16*)w;  w += (size_t)2048 * 4096 * 2;    // 16 MiB
  bf16* Zb  = (bf16*)w;  w += (size_t)NROWS * UNITS * 2;  // 32 MiB

  pack_xy_kernel<<<2048, 256, 0, stream>>>(x, y, Xbf, Ybf);
  dim3 tg(64, 32, 6);
  transpose_cvt6_kernel<<<tg, 256, 0, stream>>>(Wz, Uz, Wr, Ur, Wg, Ug, Bzr, Bgt);

  // GEMM1: [8192 x 4096] = [Y|X] @ Bzr^T -> z (bf16), rx (bf16)
  gemm256<0><<<512, 512, 0, stream>>>(Ybf, Xbf, Bzr, bz, buz, br, bur, Xbf, Zb, RX, nullptr);
  // GEMM2: [8192 x 2048] = [Y|RX] @ Bg^T -> out
  gemm256<1><<<256, 512, 0, stream>>>(Ybf, RX, Bgt, bg, bug, nullptr, nullptr, Xbf, Zb, nullptr, out);
}

// Round 14
// 421.132 us; speedup vs baseline: 1.9478x; 1.9478x over previous
//
#include <hip/hip_runtime.h>
#include <hip/hip_bf16.h>
#include <cstdint>
#include <cmath>

typedef __bf16 bf16;
typedef __bf16 bf16x8 __attribute__((ext_vector_type(8)));
typedef __bf16 bf16x4 __attribute__((ext_vector_type(4)));
typedef __bf16 bf16x2 __attribute__((ext_vector_type(2)));
typedef float f32x4 __attribute__((ext_vector_type(4)));

#define NROWS 8192
#define UNITS 2048
#define NT 64      // K = 4096 / BK(=64)
#define NSPLIT 32  // tile index where A switches from A0 to A1

__device__ __forceinline__ void gload_lds16(const bf16* g, const bf16* lds) {
  __builtin_amdgcn_global_load_lds(
      (const __attribute__((address_space(1))) uint32_t*)(uintptr_t)g,
      (__attribute__((address_space(3))) uint32_t*)(uint32_t)(uintptr_t)lds,
      16, 0, 0);
}

#define BARR do { asm volatile("" ::: "memory"); __builtin_amdgcn_s_barrier(); \
                  asm volatile("" ::: "memory"); } while (0)
#define SCHEDB do { asm volatile("" ::: "memory"); __builtin_amdgcn_sched_barrier(0); \
                    asm volatile("" ::: "memory"); } while (0)
#define WAITV(N) asm volatile("s_waitcnt vmcnt(" #N ")" ::: "memory")

__device__ __forceinline__ float fast_tanh(float v) {
  float e = __expf(2.f * v);  // saturates: +inf -> 1, 0 -> -1; no NaN
  return 1.f - 2.f / (e + 1.f);
}

// ---- pack x,y fp32 -> bf16
__global__ void pack_xy_kernel(const float* __restrict__ x, const float* __restrict__ y,
                               bf16* __restrict__ xb, bf16* __restrict__ yb) {
  size_t n4 = (size_t)NROWS * UNITS / 4;
  size_t stride = (size_t)gridDim.x * blockDim.x;
  for (size_t i = (size_t)blockIdx.x * blockDim.x + threadIdx.x; i < n4; i += stride) {
    float4 vx = ((const float4*)x)[i];
    float4 vy = ((const float4*)y)[i];
    bf16x4 ox = {(bf16)vx.x, (bf16)vx.y, (bf16)vx.z, (bf16)vx.w};
    bf16x4 oy = {(bf16)vy.x, (bf16)vy.y, (bf16)vy.z, (bf16)vy.w};
    ((bf16x4*)xb)[i] = ox;
    ((bf16x4*)yb)[i] = oy;
  }
}

// ---- fused 6-way transpose+convert, 64(k) x 32(j) tiles, bf16x2 stores (128B rows)
__global__ void transpose_cvt6_kernel(const float* __restrict__ Wz, const float* __restrict__ Uz,
                                      const float* __restrict__ Wr, const float* __restrict__ Ur,
                                      const float* __restrict__ Wg, const float* __restrict__ Ug,
                                      bf16* __restrict__ Bzr, bf16* __restrict__ Bgt) {
  __shared__ float t[64][33];
  const float* src;
  bf16* dst;
  int koff;
  switch (blockIdx.z) {
    case 0: src = Wz; dst = Bzr;                         koff = 0;    break;
    case 1: src = Uz; dst = Bzr;                         koff = 2048; break;
    case 2: src = Wr; dst = Bzr + (size_t)2048 * 4096;   koff = 0;    break;
    case 3: src = Ur; dst = Bzr + (size_t)2048 * 4096;   koff = 2048; break;
    case 4: src = Wg; dst = Bgt;                         koff = 0;    break;
    default: src = Ug; dst = Bgt;                        koff = 2048; break;
  }
  int j0 = blockIdx.x * 32, k0 = blockIdx.y * 64;
  int tx = threadIdx.x & 31, ty = threadIdx.x >> 5;  // 32 x 8
#pragma unroll
  for (int i = 0; i < 64; i += 8)
    t[ty + i][tx] = src[(size_t)(k0 + ty + i) * UNITS + j0 + tx];
  __syncthreads();
#pragma unroll
  for (int i = 0; i < 32; i += 8) {
    int j = j0 + ty + i;
    bf16x2 v = {(bf16)t[2 * tx][ty + i], (bf16)t[2 * tx + 1][ty + i]};
    *(bf16x2*)&dst[(size_t)j * 4096 + koff + k0 + 2 * tx] = v;
  }
}

// ===== 256x256 2-phase GEMM (R12 schedule, 2 s_barriers + 1 vmcnt per K-tile) =====
template <int EPI>
__global__ __launch_bounds__(512, 2)
void gemm256(const bf16* __restrict__ A0, const bf16* __restrict__ A1,
             const bf16* __restrict__ Bt,
             const float* __restrict__ bias_a, const float* __restrict__ bias_b,
             const float* __restrict__ bias_c, const float* __restrict__ bias_d,
             const bf16* __restrict__ xin, bf16* __restrict__ zbuf,
             bf16* __restrict__ rxbuf, float* __restrict__ outbuf) {
  __shared__ bf16 LDS[2][32768];  // per buf: A[0,16384) B[16384,32768)
  const int tid = threadIdx.x;
  const int wv = tid >> 6, lane = tid & 63;
  const int wr = wv >> 2, wc = wv & 3;

  // 2-D XCD patch mapping (L2 reuse for both A and B panels)
  const int nl = (int)gridDim.x >> 3;
  const int xc = (int)blockIdx.x & 7;
  const int l = (int)blockIdx.x >> 3;
  const int bxq = nl >> 4;
  const int by = (xc & 1) * 16 + (l & 15);
  const int bx = (xc >> 1) * bxq + (l >> 4);
  const int brow = by * 256;
  const int bcol = bx * 256;

  // ---- staging offsets; halves aligned with read quadrants
  const int rr = lane >> 2;
  const int kk_st = ((lane & 3) * 8) ^ ((rr & 6) << 2);  // inverse-swizzled source k
  int offA[2][2], offB[2][2], dstA[2][2], dstB[2][2];
#pragma unroll
  for (int H = 0; H < 2; ++H)
#pragma unroll
    for (int c = 0; c < 2; ++c) {
      int ssA = H * 8 + wv;
      offA[H][c] = (brow + c * 128 + (ssA >> 1) * 16 + rr) * 2048 + (ssA & 1) * 32 + kk_st;
      dstA[H][c] = c * 8192 + ssA * 512;
      int ssB = (wv >> 2) * 8 + H * 4 + (wv & 3);
      offB[H][c] = (bcol + c * 128 + (ssB >> 1) * 16 + rr) * 4096 + (ssB & 1) * 32 + kk_st;
      dstB[H][c] = 16384 + c * 8192 + ssB * 512;
    }

  // ---- fragment read offsets (swizzled; conflict-free 16x16 geometry)
  const int lr = lane & 15;
  const int kread = ((lane >> 4) * 8) ^ ((lr & 6) << 2);
  const int abase = wr * 8192 + lr * 32 + kread;
  const int bbase = 16384 + (wc >> 1) * 8192 + (wc & 1) * 4096 + lr * 32 + kread;

#define ST_A(TI, H, BUF)                                                      \
  if ((TI) < NT) {                                                            \
    const bf16* _s = ((TI) < NSPLIT) ? A0 + (size_t)(TI)*64                   \
                                     : A1 + (size_t)((TI)-NSPLIT) * 64;       \
    gload_lds16(_s + offA[H][0], (BUF) + dstA[H][0]);                         \
    gload_lds16(_s + offA[H][1], (BUF) + dstA[H][1]);                         \
  }
#define ST_B(TI, H, BUF)                                                      \
  if ((TI) < NT) {                                                            \
    const bf16* _s = Bt + (size_t)(TI)*64;                                    \
    gload_lds16(_s + offB[H][0], (BUF) + dstB[H][0]);                         \
    gload_lds16(_s + offB[H][1], (BUF) + dstB[H][1]);                         \
  }
#define RD_B(DST, LP, NB)                                                     \
  _Pragma("unroll") for (int kh = 0; kh < 2; ++kh)                            \
  _Pragma("unroll") for (int n = 0; n < 2; ++n)                               \
      DST[n][kh] = *(const bf16x8*)((LP) + bbase + ((n + 2 * (NB)) * 2 + kh) * 512);
#define RD_A(DST, LP, MB)                                                     \
  _Pragma("unroll") for (int kh = 0; kh < 2; ++kh)                            \
  _Pragma("unroll") for (int m = 0; m < 4; ++m)                               \
      DST[m][kh] = *(const bf16x8*)((LP) + abase + ((m + 4 * (MB)) * 2 + kh) * 512);
#define MFMA_Q(AARR, BARR_, MOFF, NOFF)                                       \
  __builtin_amdgcn_s_setprio(1);                                              \
  _Pragma("unroll") for (int kh = 0; kh < 2; ++kh)                            \
  _Pragma("unroll") for (int m = 0; m < 4; ++m)                               \
  _Pragma("unroll") for (int n = 0; n < 2; ++n)                               \
      acc[m + MOFF][n + NOFF] = __builtin_amdgcn_mfma_f32_16x16x32_bf16(      \
          AARR[m][kh], BARR_[n][kh], acc[m + MOFF][n + NOFF], 0, 0, 0);       \
  __builtin_amdgcn_s_setprio(0);

  f32x4 acc[8][4];
#pragma unroll
  for (int m = 0; m < 8; ++m)
#pragma unroll
    for (int n = 0; n < 4; ++n) {
      f32x4 zz = {0.f, 0.f, 0.f, 0.f};
      acc[m][n] = zz;
    }

  bf16x8 a0[4][2], a1[4][2], b0[2][2], b1[2][2];

  // ---- prologue: tile0 full + [B(1)h0, A(1)h0] in flight (steady queue shape) ----
  {
    bf16* L0 = &LDS[0][0];
    bf16* L1 = &LDS[1][0];
    ST_A(0, 0, L0); ST_B(0, 0, L0); ST_A(0, 1, L0); ST_B(0, 1, L0);
    ST_B(1, 0, L1); ST_A(1, 0, L1);
    WAITV(4);  // confirm tile0 (8 loads); leave [B(1)h0, A(1)h0]
    BARR;
  }

  // Per tile t (R12 schedule; pre-MFMA s_barriers proven redundant -> sched_barrier):
  //  PhA: st A(t+1)h1->N, B(t+1)h1->N; rd a0,b0,b1; SCHEDB;
  //       Q a0*b0, Q a0*b1; BARR
  //  PhB: st B(t+2)h0->C, A(t+2)h0->C; rd a1; SCHEDB;
  //       Q a1*b0, Q a1*b1; WAITV(WB); BARR
  // Steady WB=4 confirms all of tile t+1, leaves [B(t+2)h0, A(t+2)h0].
#define TILE(T, CUR, NXT, WB)                                                 \
  {                                                                           \
    const bf16* Lc = &LDS[CUR][0];                                            \
    bf16* Lcw = &LDS[CUR][0];                                                 \
    bf16* Lnw = &LDS[NXT][0];                                                 \
    /* PhA */                                                                 \
    ST_A((T) + 1, 1, Lnw);                                                    \
    ST_B((T) + 1, 1, Lnw);                                                    \
    RD_A(a0, Lc, 0);                                                          \
    RD_B(b0, Lc, 0);                                                          \
    RD_B(b1, Lc, 1);                                                          \
    SCHEDB;                                                                   \
    MFMA_Q(a0, b0, 0, 0);                                                     \
    MFMA_Q(a0, b1, 0, 2);                                                     \
    BARR;                                                                     \
    /* PhB */                                                                 \
    ST_B((T) + 2, 0, Lcw);                                                    \
    ST_A((T) + 2, 0, Lcw);                                                    \
    RD_A(a1, Lc, 1);                                                          \
    SCHEDB;                                                                   \
    MFMA_Q(a1, b0, 4, 0);                                                     \
    MFMA_Q(a1, b1, 4, 2);                                                     \
    WAITV(WB); BARR;                                                          \
  }

#pragma unroll 1
  for (int t = 0; t < NT - 2; t += 2) {
    TILE(t, 0, 1, 4);
    TILE(t + 1, 1, 0, 4);
  }
  TILE(NT - 2, 0, 1, 0);
  TILE(NT - 1, 1, 0, 0);

  // ---- epilogue: C/D layout col=lane&15, row=(lane>>4)*4+q ----
  const int lq = (lane >> 4) << 2;
  const int lc = lane & 15;
  const int rowb = brow + wr * 128;
  const int colb = bcol + wc * 64;
  if constexpr (EPI == 0) {
    if (bcol < UNITS) {
#pragma unroll
      for (int m = 0; m < 8; ++m)
#pragma unroll
        for (int n = 0; n < 4; ++n) {
          int col = colb + n * 16 + lc;
          float ba = bias_a[col] + bias_b[col];
#pragma unroll
          for (int q = 0; q < 4; ++q) {
            int row = rowb + m * 16 + lq + q;
            zbuf[(size_t)row * UNITS + col] = (bf16)(acc[m][n][q] + ba);
          }
        }
    } else {
#pragma unroll
      for (int m = 0; m < 8; ++m)
#pragma unroll
        for (int n = 0; n < 4; ++n) {
          int col = colb - UNITS + n * 16 + lc;
          float bc = bias_c[col] + bias_d[col];
#pragma unroll
          for (int q = 0; q < 4; ++q) {
            int row = rowb + m * 16 + lq + q;
            size_t idx = (size_t)row * UNITS + col;
            float r = acc[m][n][q] + bc;
            rxbuf[idx] = (bf16)(r * (float)xin[idx]);
          }
        }
    }
  } else {
#pragma unroll
    for (int m = 0; m < 8; ++m)
#pragma unroll
      for (int n = 0; n < 4; ++n) {
        int col = colb + n * 16 + lc;
        float bg_ = bias_a[col] + bias_b[col];
#pragma unroll
        for (int q = 0; q < 4; ++q) {
          int row = rowb + m * 16 + lq + q;
          size_t idx = (size_t)row * UNITS + col;
          float h = fast_tanh(acc[m][n][q] + bg_);
          float zv = (float)zbuf[idx];
          float xv = (float)xin[idx];
          outbuf[idx] = (1.f - zv) * xv + zv * h;
        }
      }
  }
#undef ST_A
#undef ST_B
#undef RD_A
#undef RD_B
#undef MFMA_Q
#undef TILE
}

extern "C" void kernel_launch(void* const* d_in, const int* in_sizes, int n_in,
                              void* d_out, int out_size, void* d_ws, size_t ws_size,
                              hipStream_t stream) {
  const float* x   = (const float*)d_in[0];
  const float* y   = (const float*)d_in[1];
  const float* Wz  = (const float*)d_in[2];
  const float* bz  = (const float*)d_in[3];
  const float* Uz  = (const float*)d_in[4];
  const float* buz = (const float*)d_in[5];
  const float* Wr  = (const float*)d_in[6];
  const float* br  = (const float*)d_in[7];
  const float* Ur  = (const float*)d_in[8];
  const float* bur = (const float*)d_in[9];
  const float* Wg  = (const float*)d_in[10];
  const float* bg  = (const float*)d_in[11];
  const float* Ug  = (const float*)d_in[12];
  const float* bug = (const float*)d_in[13];
  float* out = (float*)d_out;

  char* w = (char*)d_ws;
  bf16* Ybf = (bf16*)w;  w += (size_t)NROWS * UNITS * 2;  // 32 MiB
  bf16* Xbf = (bf16*)w;  w += (size_t)NROWS * UNITS * 2;  // 32 MiB
  bf16* RX  = (bf16*)w;  w += (size_t)NROWS * UNITS * 2;  // 32 MiB
  bf16* Bzr = (bf16*)w;  w += (size_t)4096 * 4096 * 2;    // 32 MiB
  bf16* Bgt = (bf16*)w;  w += (size_t)2048 * 4096 * 2;    // 16 MiB
  bf16* Zb  = (bf16*)w;  w += (size_t)NROWS * UNITS * 2;  // 32 MiB

  pack_xy_kernel<<<2048, 256, 0, stream>>>(x, y, Xbf, Ybf);
  dim3 tg(64, 32, 6);
  transpose_cvt6_kernel<<<tg, 256, 0, stream>>>(Wz, Uz, Wr, Ur, Wg, Ug, Bzr, Bgt);

  // GEMM1: [8192 x 4096] = [Y|X] @ Bzr^T -> z (bf16), rx (bf16)
  gemm256<0><<<512, 512, 0, stream>>>(Ybf, Xbf, Bzr, bz, buz, br, bur, Xbf, Zb, RX, nullptr);
  // GEMM2: [8192 x 2048] = [Y|RX] @ Bg^T -> out
  gemm256<1><<<256, 512, 0, stream>>>(Ybf, RX, Bgt, bg, bug, nullptr, nullptr, Xbf, Zb, nullptr, out);
}